// Round 7
// baseline (54.591 us; speedup 1.0000x reference)
//
#include <hip/hip_runtime.h>
#include <hip/hip_bf16.h>
#include <stdint.h>
#include <stddef.h>

// ---------------------------------------------------------------------------
// SSRupsampling3 == two small GEMMs:
//   T  = f(Wbig[384x512] @ x)     (relu+bias rows 128..383)
//   out= W2[512x384] @ T          (+ pixel-shuffle scatter)
// R7: 2-tile pipelined block (64 px/tile, 256 blocks, 1 block/CU).
//   P1(t0) ; { P2(t0) || P1(t1) } ; P2 tail ; store(t0) ; P2(t1) ; store(t1)
// Overlaps the x-HBM-read pipe (P1) with the out-write + L2-weight + MFMA
// pipes (P2), which R3-R6 ran sequentially (all plateaued ~41 us).
// ---------------------------------------------------------------------------

typedef __attribute__((ext_vector_type(8))) __bf16 bf16x8;
typedef __attribute__((ext_vector_type(4))) float  f32x4;
typedef __attribute__((ext_vector_type(2))) float  f32x2;
typedef __attribute__((ext_vector_type(4))) unsigned int u32x4;
typedef __attribute__((ext_vector_type(2))) unsigned int u32x2;

#define BAR() asm volatile("s_waitcnt lgkmcnt(0)\n\ts_barrier" ::: "memory")

// A-fragment layout for mfma_f32_16x16x32_bf16 (verified R1-R6):
//   lane l holds A[row = mfrag*16 + (l&15)][k = gks*32 + (l>>4)*8 + j]
// Stored as frag[(gks*NMF + mfrag)*512 + lane*8 + j] (bf16).

// ---------------- prep kernel (unchanged since R4, ~5 us) -------------------

__global__ __launch_bounds__(256) void prep_k(
    const float* __restrict__ w_ch, const float* __restrict__ w_1x1,
    const float* __restrict__ w_lr, const float* __restrict__ w_du,
    const float* __restrict__ w_H,  const float* __restrict__ w_w,
    __bf16* __restrict__ Wf, __bf16* __restrict__ W2f)
{
  __shared__ float wh[2][128];
  __shared__ float Mrow[2][128];
  int bid = blockIdx.x;
  if (bid < 768) {
    int gid = bid * 256 + threadIdx.x;       // 196608 = 384*512
    int r = gid >> 9, c = gid & 511;
    float v;
    if (r < 128) {                            // w_ch[:, :128] @ w_1x1
      const float* a_ = w_ch + r * 384;
      const float* b_ = w_1x1 + c;
      float s0 = 0.f, s1 = 0.f, s2 = 0.f, s3 = 0.f;
      #pragma unroll
      for (int j = 0; j < 128; j += 4) {
        s0 += a_[j + 0] * b_[(size_t)(j + 0) * 512];
        s1 += a_[j + 1] * b_[(size_t)(j + 1) * 512];
        s2 += a_[j + 2] * b_[(size_t)(j + 2) * 512];
        s3 += a_[j + 3] * b_[(size_t)(j + 3) * 512];
      }
      v = (s0 + s1) + (s2 + s3);
    } else if (r < 256) {
      v = w_lr[(r - 128) * 1536 + c * 3 + 1]; // center tap (1,3)
    } else {
      v = w_du[(r - 256) * 1536 + c * 3 + 1]; // center tap (3,1)
    }
    int gks = c >> 5, lsub = (c >> 3) & 3, jj = c & 7;
    int mfrag = r >> 4, lrow = r & 15;
    Wf[((gks * 24 + mfrag) << 9) + ((lrow + 16 * lsub) << 3) + jj] = (__bf16)v;
  } else {
    int t = threadIdx.x & 127, half = threadIdx.x >> 7;
    int r = (bid - 768) * 2 + half;           // W2 row, 0..511
    int beta = r >> 8, gam = r & 1, irow = (r >> 1) & 127;
    wh[half][t] = w_H[(gam * 128 + irow) * 128 + t];
    __syncthreads();
    {
      const float* ww = w_w + beta * 16384 + t;
      float s0 = 0.f, s1 = 0.f, s2 = 0.f, s3 = 0.f;
      #pragma unroll
      for (int s = 0; s < 128; s += 4) {
        s0 += wh[half][s + 0] * ww[(s + 0) * 128];
        s1 += wh[half][s + 1] * ww[(s + 1) * 128];
        s2 += wh[half][s + 2] * ww[(s + 2) * 128];
        s3 += wh[half][s + 3] * ww[(s + 3) * 128];
      }
      Mrow[half][t] = (s0 + s1) + (s2 + s3);
    }
    __syncthreads();
    int mfrag = r >> 4, lrow = r & 15;
    #pragma unroll
    for (int c0 = 0; c0 < 384; c0 += 128) {
      int col = c0 + t;
      float v;
      if (c0 == 0) {
        v = Mrow[half][t];
      } else {
        const float* wc = w_ch + col;
        float s0 = 0.f, s1 = 0.f, s2 = 0.f, s3 = 0.f;
        #pragma unroll
        for (int k = 0; k < 128; k += 4) {
          s0 += Mrow[half][k + 0] * wc[(k + 0) * 384];
          s1 += Mrow[half][k + 1] * wc[(k + 1) * 384];
          s2 += Mrow[half][k + 2] * wc[(k + 2) * 384];
          s3 += Mrow[half][k + 3] * wc[(k + 3) * 384];
        }
        v = (s0 + s1) + (s2 + s3);
      }
      int gks = col >> 5, lsub = (col >> 3) & 3, jj = col & 7;
      W2f[((gks * 32 + mfrag) << 9) + ((lrow + 16 * lsub) << 3) + jj] = (__bf16)v;
    }
  }
}

// ---------------- fused kernel ----------------------------------------------

__device__ __forceinline__ int swzB(int px) {
  return (((px & 7) ^ ((px >> 3) & 7)) << 4);
}

__global__ __launch_bounds__(512, 2) void fused_k(
    const float* __restrict__ x, const __bf16* __restrict__ Wf,
    const __bf16* __restrict__ W2f,
    const float* __restrict__ b_lr, const float* __restrict__ b_du,
    float* __restrict__ out)
{
  __shared__ __align__(16) char smem[114688];
  char* Tlds0 = smem;                    // 64 px * 768 B
  char* Tlds1 = smem + 49152;
  char* buf0  = smem + 98304;            // 64 px * 128 B (BK=64)
  char* buf1  = smem + 98304 + 8192;

  const int tid  = threadIdx.x;
  const int lane = tid & 63;
  const int wv   = tid >> 6;          // 0..7
  const int l15  = lane & 15, lg = lane >> 4;

  const int p0   = blockIdx.x * 128;
  const int img  = p0 >> 12;
  const int pixA = p0 & 4095;
  const int pixB = pixA + 64;
  const float* xbA = x + (size_t)img * (512 * 4096) + pixA;
  const float* xbB = xbA + 64;
  const char* Wfb  = (const char*)Wf;
  const char* W2b  = (const char*)W2f;

  // x staging: 512 threads; 4 px x 2 k each (1-deep prefetch, proven R5)
  const int sp4 = (tid & 15) * 4;
  const int skp = (tid >> 4) * 2;

  f32x4 ldv[2];
  auto issueS = [&](const float* xb, int kt) {
    ldv[0] = *(const f32x4*)(xb + (size_t)(kt * 64 + skp) * 4096 + sp4);
    ldv[1] = *(const f32x4*)(xb + (size_t)(kt * 64 + skp + 1) * 4096 + sp4);
  };
  auto writeS = [&](char* bw) {
    #pragma unroll
    for (int pi = 0; pi < 4; ++pi) {
      int px = sp4 + pi;
      union { __bf16 b[2]; unsigned int u; } wd;
      wd.b[0] = (__bf16)ldv[0][pi];
      wd.b[1] = (__bf16)ldv[1][pi];
      *(unsigned int*)(bw + px * 128 + ((skp * 2) ^ swzB(px))) = wd.u;
    }
  };

  f32x4 acc1[3][4];
  f32x4 acc2[4][4];
  #pragma unroll
  for (int i = 0; i < 3; ++i)
    #pragma unroll
    for (int j = 0; j < 4; ++j) acc1[i][j] = f32x4{0.f, 0.f, 0.f, 0.f};
  #pragma unroll
  for (int i = 0; i < 4; ++i)
    #pragma unroll
    for (int j = 0; j < 4; ++j) acc2[i][j] = f32x4{0.f, 0.f, 0.f, 0.f};

  // P1 compute step: 24 MFMA into acc1
  auto compute1 = [&](int kt, const char* bbuf) {
    #pragma unroll
    for (int ks = 0; ks < 2; ++ks) {
      bf16x8 af[3];
      #pragma unroll
      for (int i = 0; i < 3; ++i)
        af[i] = *(const bf16x8*)(Wfb +
            (((kt * 2 + ks) * 24 + wv * 3 + i) << 10) + lane * 16);
      bf16x8 bfr[4];
      #pragma unroll
      for (int j = 0; j < 4; ++j) {
        int rb = j * 16 + l15;
        bfr[j] = *(const bf16x8*)(bbuf + rb * 128 +
                                  ((ks * 64 + lg * 16) ^ swzB(rb)));
      }
      __builtin_amdgcn_s_setprio(1);
      #pragma unroll
      for (int i = 0; i < 3; ++i)
        #pragma unroll
        for (int j = 0; j < 4; ++j)
          acc1[i][j] = __builtin_amdgcn_mfma_f32_16x16x32_bf16(
              af[i], bfr[j], acc1[i][j], 0, 0, 0);
      __builtin_amdgcn_s_setprio(0);
    }
  };

  // P1 epilogue: bias+relu rows>=128, T' -> Tl [px][384] bf16
  auto epi1 = [&](char* Tl) {
    #pragma unroll
    for (int i = 0; i < 3; ++i) {
      int m0 = wv * 48 + i * 16 + lg * 4;
      bool rl = (m0 >= 128);
      const float* bp = (m0 >= 256) ? (b_du + (m0 - 256)) : (b_lr + (m0 - 128));
      float b0 = 0.f, b1 = 0.f, b2 = 0.f, b3 = 0.f;
      if (rl) { b0 = bp[0]; b1 = bp[1]; b2 = bp[2]; b3 = bp[3]; }
      #pragma unroll
      for (int j = 0; j < 4; ++j) {
        int p = j * 16 + l15;
        union { __bf16 b[4]; u32x2 u; } wd;
        float v0 = acc1[i][j][0], v1 = acc1[i][j][1];
        float v2 = acc1[i][j][2], v3 = acc1[i][j][3];
        if (rl) {
          v0 = fmaxf(v0 + b0, 0.f); v1 = fmaxf(v1 + b1, 0.f);
          v2 = fmaxf(v2 + b2, 0.f); v3 = fmaxf(v3 + b3, 0.f);
        }
        wd.b[0] = (__bf16)v0; wd.b[1] = (__bf16)v1;
        wd.b[2] = (__bf16)v2; wd.b[3] = (__bf16)v3;
        *(u32x2*)(Tl + p * 768 + ((m0 * 2) ^ ((p & 7) << 4))) = wd.u;
      }
    }
  };

  bf16x8 af2A[4], af2B[4];
  auto loadAf2 = [&](int g, bf16x8* af) {
    #pragma unroll
    for (int i = 0; i < 4; ++i)
      af[i] = *(const bf16x8*)(W2b + ((g * 32 + wv * 4 + i) << 10) + lane * 16);
  };
  // P2 step: 16 MFMA into acc2
  auto P2step = [&](int g, const bf16x8* af, const char* Tl) {
    bf16x8 bfr[4];
    #pragma unroll
    for (int j = 0; j < 4; ++j) {
      int rb = j * 16 + l15;
      bfr[j] = *(const bf16x8*)(Tl + rb * 768 +
                                ((g * 64 + lg * 16) ^ ((rb & 7) << 4)));
    }
    __builtin_amdgcn_s_setprio(1);
    #pragma unroll
    for (int i = 0; i < 4; ++i)
      #pragma unroll
      for (int j = 0; j < 4; ++j)
        acc2[i][j] = __builtin_amdgcn_mfma_f32_16x16x32_bf16(
            af[i], bfr[j], acc2[i][j], 0, 0, 0);
    __builtin_amdgcn_s_setprio(0);
  };

  // pixel-shuffle scatter: row r = beta*256 + irow*2 + gamma
  auto storeOut = [&](int pixb) {
    #pragma unroll
    for (int i = 0; i < 4; ++i) {
      int r = wv * 64 + i * 16 + lg * 4;   // even
      int beta = r >> 8;
      int irow = (r >> 1) & 127;
      #pragma unroll
      for (int j = 0; j < 4; ++j) {
        int pp = pixb + j * 16 + l15;
        int h = pp >> 6, w = pp & 63;
        size_t o0 = ((((size_t)img * 128 + irow) * 128) + (2 * h + beta)) * 128
                    + 2 * w;
        f32x2 lo; lo.x = acc2[i][j][0]; lo.y = acc2[i][j][1];
        f32x2 hi; hi.x = acc2[i][j][2]; hi.y = acc2[i][j][3];
        *(f32x2*)(out + o0)         = lo;   // channel irow
        *(f32x2*)(out + o0 + 16384) = hi;   // channel irow+1
      }
    }
  };

  // ======================= P1(t0) =========================================
  issueS(xbA, 0);
  writeS(buf0);
  issueS(xbA, 1);
  BAR();
  #pragma unroll 1
  for (int kt2 = 0; kt2 < 8; kt2 += 2) {
    compute1(kt2, buf0);
    writeS(buf1);                       // kt2+1 data
    if (kt2 < 6) issueS(xbA, kt2 + 2);
    BAR();
    compute1(kt2 + 1, buf1);
    if (kt2 < 6) {
      writeS(buf0);                     // kt2+2 data
      issueS(xbA, kt2 + 3);
      BAR();
    }
  }

  // ---- transition t0 -> t1 ----
  issueS(xbB, 0);                        // start t1 x stream ASAP
  epi1(Tlds0);                           // T'(t0) -> LDS
  writeS(buf0);
  issueS(xbB, 1);
  #pragma unroll
  for (int i = 0; i < 3; ++i)
    #pragma unroll
    for (int j = 0; j < 4; ++j) acc1[i][j] = f32x4{0.f, 0.f, 0.f, 0.f};
  loadAf2(0, af2A);
  BAR();

  // ============== merged: P2(t0) g=0..7  ||  P1(t1) kt=0..7 ===============
  #pragma unroll 1
  for (int g2 = 0; g2 < 8; g2 += 2) {
    loadAf2(g2 + 1, af2B);
    P2step(g2, af2A, Tlds0);
    compute1(g2, buf0);
    writeS(buf1);
    if (g2 < 6) issueS(xbB, g2 + 2);
    BAR();
    loadAf2(g2 + 2, af2A);
    P2step(g2 + 1, af2B, Tlds0);
    compute1(g2 + 1, buf1);
    if (g2 < 6) {
      writeS(buf0);
      issueS(xbB, g2 + 3);
      BAR();
    }
  }

  // ============== P2(t0) tail g=8..11 (barrier-free) ======================
  #pragma unroll 1
  for (int g2 = 8; g2 < 12; g2 += 2) {
    loadAf2(g2 + 1, af2B);
    P2step(g2, af2A, Tlds0);
    if (g2 < 10) loadAf2(g2 + 2, af2A);
    P2step(g2 + 1, af2B, Tlds0);
  }

  storeOut(pixA);                        // t0 out; stores drain async
  epi1(Tlds1);                           // T'(t1) -> LDS
  #pragma unroll
  for (int i = 0; i < 4; ++i)
    #pragma unroll
    for (int j = 0; j < 4; ++j) acc2[i][j] = f32x4{0.f, 0.f, 0.f, 0.f};
  loadAf2(0, af2A);
  BAR();

  // ======================= P2(t1) (barrier-free) ==========================
  #pragma unroll 1
  for (int g2 = 0; g2 < 12; g2 += 2) {
    loadAf2(g2 + 1, af2B);
    P2step(g2, af2A, Tlds1);
    if (g2 < 10) loadAf2(g2 + 2, af2A);
    P2step(g2 + 1, af2B, Tlds1);
  }
  storeOut(pixB);
}

// ---------------- launcher ---------------------------------------------------

extern "C" void kernel_launch(void* const* d_in, const int* in_sizes, int n_in,
                              void* d_out, int out_size, void* d_ws, size_t ws_size,
                              hipStream_t stream) {
  const float* x     = (const float*)d_in[0];
  const float* w_du  = (const float*)d_in[1];
  const float* b_du  = (const float*)d_in[2];
  const float* w_lr  = (const float*)d_in[3];
  const float* b_lr  = (const float*)d_in[4];
  const float* w_1x1 = (const float*)d_in[5];
  const float* w_ch  = (const float*)d_in[6];
  const float* w_w   = (const float*)d_in[7];
  const float* w_H   = (const float*)d_in[8];
  float* out = (float*)d_out;

  char* ws = (char*)d_ws;
  __bf16* Wf  = (__bf16*)(ws + 0);        // 16*24*1024 = 393216
  __bf16* W2f = (__bf16*)(ws + 393216);   // 12*32*1024 = 393216
  if (ws_size < (size_t)786432) return;

  prep_k <<<1024, 256, 0, stream>>>(w_ch, w_1x1, w_lr, w_du, w_H, w_w, Wf, W2f);
  fused_k<<<256, 512, 0, stream>>>(x, Wf, W2f, b_lr, b_du, out);
}

// Round 8
// 48.876 us; speedup vs baseline: 1.1169x; 1.1169x over previous
//
#include <hip/hip_runtime.h>
#include <hip/hip_bf16.h>
#include <stdint.h>
#include <stddef.h>

// ---------------------------------------------------------------------------
// SSRupsampling3 == two small GEMMs:
//   T  = f(Wbig[384x512] @ x)     (relu+bias rows 128..383)
//   out= W2[512x384] @ T          (+ pixel-shuffle scatter)
// R8 = R5 (best known, 41.3us fused) + ONE change: fully-unrolled phase-1
// K-loop with 3-deep x prefetch (static slot rotation L[3], SROA-safe).
// Issue distance ~2 compute phases (+2 barriers) > HBM latency (~900cy).
// ---------------------------------------------------------------------------

typedef __attribute__((ext_vector_type(8))) __bf16 bf16x8;
typedef __attribute__((ext_vector_type(4))) float  f32x4;
typedef __attribute__((ext_vector_type(2))) float  f32x2;
typedef __attribute__((ext_vector_type(4))) unsigned int u32x4;
typedef __attribute__((ext_vector_type(2))) unsigned int u32x2;

#define BAR() asm volatile("s_waitcnt lgkmcnt(0)\n\ts_barrier" ::: "memory")

// A-fragment layout for mfma_f32_16x16x32_bf16 (verified R1-R7):
//   lane l holds A[row = mfrag*16 + (l&15)][k = gks*32 + (l>>4)*8 + j]
// Stored as frag[(gks*NMF + mfrag)*512 + lane*8 + j] (bf16).

// ---------------- prep kernel (unchanged since R4, ~5 us) -------------------

__global__ __launch_bounds__(256) void prep_k(
    const float* __restrict__ w_ch, const float* __restrict__ w_1x1,
    const float* __restrict__ w_lr, const float* __restrict__ w_du,
    const float* __restrict__ w_H,  const float* __restrict__ w_w,
    __bf16* __restrict__ Wf, __bf16* __restrict__ W2f)
{
  __shared__ float wh[2][128];
  __shared__ float Mrow[2][128];
  int bid = blockIdx.x;
  if (bid < 768) {
    int gid = bid * 256 + threadIdx.x;       // 196608 = 384*512
    int r = gid >> 9, c = gid & 511;
    float v;
    if (r < 128) {                            // w_ch[:, :128] @ w_1x1
      const float* a_ = w_ch + r * 384;
      const float* b_ = w_1x1 + c;
      float s0 = 0.f, s1 = 0.f, s2 = 0.f, s3 = 0.f;
      #pragma unroll
      for (int j = 0; j < 128; j += 4) {
        s0 += a_[j + 0] * b_[(size_t)(j + 0) * 512];
        s1 += a_[j + 1] * b_[(size_t)(j + 1) * 512];
        s2 += a_[j + 2] * b_[(size_t)(j + 2) * 512];
        s3 += a_[j + 3] * b_[(size_t)(j + 3) * 512];
      }
      v = (s0 + s1) + (s2 + s3);
    } else if (r < 256) {
      v = w_lr[(r - 128) * 1536 + c * 3 + 1]; // center tap (1,3)
    } else {
      v = w_du[(r - 256) * 1536 + c * 3 + 1]; // center tap (3,1)
    }
    int gks = c >> 5, lsub = (c >> 3) & 3, jj = c & 7;
    int mfrag = r >> 4, lrow = r & 15;
    Wf[((gks * 24 + mfrag) << 9) + ((lrow + 16 * lsub) << 3) + jj] = (__bf16)v;
  } else {
    int t = threadIdx.x & 127, half = threadIdx.x >> 7;
    int r = (bid - 768) * 2 + half;           // W2 row, 0..511
    int beta = r >> 8, gam = r & 1, irow = (r >> 1) & 127;
    wh[half][t] = w_H[(gam * 128 + irow) * 128 + t];
    __syncthreads();
    {
      const float* ww = w_w + beta * 16384 + t;
      float s0 = 0.f, s1 = 0.f, s2 = 0.f, s3 = 0.f;
      #pragma unroll
      for (int s = 0; s < 128; s += 4) {
        s0 += wh[half][s + 0] * ww[(s + 0) * 128];
        s1 += wh[half][s + 1] * ww[(s + 1) * 128];
        s2 += wh[half][s + 2] * ww[(s + 2) * 128];
        s3 += wh[half][s + 3] * ww[(s + 3) * 128];
      }
      Mrow[half][t] = (s0 + s1) + (s2 + s3);
    }
    __syncthreads();
    int mfrag = r >> 4, lrow = r & 15;
    #pragma unroll
    for (int c0 = 0; c0 < 384; c0 += 128) {
      int col = c0 + t;
      float v;
      if (c0 == 0) {
        v = Mrow[half][t];
      } else {
        const float* wc = w_ch + col;
        float s0 = 0.f, s1 = 0.f, s2 = 0.f, s3 = 0.f;
        #pragma unroll
        for (int k = 0; k < 128; k += 4) {
          s0 += Mrow[half][k + 0] * wc[(k + 0) * 384];
          s1 += Mrow[half][k + 1] * wc[(k + 1) * 384];
          s2 += Mrow[half][k + 2] * wc[(k + 2) * 384];
          s3 += Mrow[half][k + 3] * wc[(k + 3) * 384];
        }
        v = (s0 + s1) + (s2 + s3);
      }
      int gks = col >> 5, lsub = (col >> 3) & 3, jj = col & 7;
      W2f[((gks * 32 + mfrag) << 9) + ((lrow + 16 * lsub) << 3) + jj] = (__bf16)v;
    }
  }
}

// ---------------- fused kernel ----------------------------------------------

__device__ __forceinline__ int swzB(int px) {
  return (((px & 7) ^ ((px >> 3) & 7)) << 4);
}

__global__ __launch_bounds__(512, 4) void fused_k(
    const float* __restrict__ x, const __bf16* __restrict__ Wf,
    const __bf16* __restrict__ W2f,
    const float* __restrict__ b_lr, const float* __restrict__ b_du,
    float* __restrict__ out)
{
  __shared__ __align__(16) char smem[49152 + 16384];
  char* Tlds = smem;                 // 64 px * 768 B (384 k bf16), swizzled
  char* buf0 = smem + 49152;         // 64 px * 128 B
  char* buf1 = smem + 49152 + 8192;

  const int tid  = threadIdx.x;
  const int lane = tid & 63;
  const int wv   = tid >> 6;          // 0..7
  const int l15  = lane & 15, lg = lane >> 4;

  const int p0      = blockIdx.x * 64;
  const int img     = p0 >> 12;
  const int pixbase = p0 & 4095;
  const float* xb   = x + (size_t)img * (512 * 4096) + pixbase;
  const char* Wfb   = (const char*)Wf;
  const char* W2b   = (const char*)W2f;

  // staging: all 512 threads; 4 px x 2 k each (two f32x4 loads -> 4 u32 writes)
  const int sp4 = (tid & 15) * 4;     // pixel quad
  const int skp = (tid >> 4) * 2;     // k pair, 0..62

  // 3-deep prefetch slots; all indices compile-time after full unroll (SROA).
  f32x4 L[3][2];
  auto issueS = [&](int kt, int slot) {
    L[slot][0] = *(const f32x4*)(xb + (size_t)(kt * 64 + skp) * 4096 + sp4);
    L[slot][1] = *(const f32x4*)(xb + (size_t)(kt * 64 + skp + 1) * 4096 + sp4);
  };
  auto writeS = [&](int slot, char* bw) {
    #pragma unroll
    for (int pi = 0; pi < 4; ++pi) {
      int px = sp4 + pi;
      union { __bf16 b[2]; unsigned int u; } wd;
      wd.b[0] = (__bf16)L[slot][0][pi];
      wd.b[1] = (__bf16)L[slot][1][pi];
      *(unsigned int*)(bw + px * 128 + ((skp * 2) ^ swzB(px))) = wd.u;
    }
  };

  // ---------------- phase 1: T = f(Wbig @ x_tile) ----------------
  f32x4 acc1[3][4] = {};

  auto compute1 = [&](int kt, const char* bbuf) {
    #pragma unroll
    for (int ks = 0; ks < 2; ++ks) {
      bf16x8 af[3];
      #pragma unroll
      for (int i = 0; i < 3; ++i)
        af[i] = *(const bf16x8*)(Wfb +
            (((kt * 2 + ks) * 24 + wv * 3 + i) << 10) + lane * 16);
      bf16x8 bfr[4];
      #pragma unroll
      for (int j = 0; j < 4; ++j) {
        int rb = j * 16 + l15;
        bfr[j] = *(const bf16x8*)(bbuf + rb * 128 +
                                  ((ks * 64 + lg * 16) ^ swzB(rb)));
      }
      __builtin_amdgcn_s_setprio(1);
      #pragma unroll
      for (int i = 0; i < 3; ++i)
        #pragma unroll
        for (int j = 0; j < 4; ++j)
          acc1[i][j] = __builtin_amdgcn_mfma_f32_16x16x32_bf16(
              af[i], bfr[j], acc1[i][j], 0, 0, 0);
      __builtin_amdgcn_s_setprio(0);
    }
  };

  issueS(0, 0);
  issueS(1, 1);
  issueS(2, 2);
  writeS(0, buf0);      // waits vmcnt(4) internally (slots 1,2 stay in flight)
  BAR();

  // fully unrolled: slot indices (kt%3) and buffer parity (kt&1) are static.
  #pragma unroll
  for (int kt = 0; kt < 8; ++kt) {
    if (kt <= 4) issueS(kt + 3, kt % 3);           // refill freed slot
    compute1(kt, (kt & 1) ? buf1 : buf0);
    if (kt < 7) writeS((kt + 1) % 3, (kt & 1) ? buf0 : buf1);
    if (kt < 7) BAR();
  }

  // epilogue 1: bias+relu rows>=128, write T' to Tlds [px][384] bf16
  #pragma unroll
  for (int i = 0; i < 3; ++i) {
    int m0 = wv * 48 + i * 16 + lg * 4;
    bool rl = (m0 >= 128);
    const float* bp = (m0 >= 256) ? (b_du + (m0 - 256)) : (b_lr + (m0 - 128));
    float b0 = 0.f, b1 = 0.f, b2 = 0.f, b3 = 0.f;
    if (rl) { b0 = bp[0]; b1 = bp[1]; b2 = bp[2]; b3 = bp[3]; }
    #pragma unroll
    for (int j = 0; j < 4; ++j) {
      int p = j * 16 + l15;
      union { __bf16 b[4]; u32x2 u; } wd;
      float v0 = acc1[i][j][0], v1 = acc1[i][j][1];
      float v2 = acc1[i][j][2], v3 = acc1[i][j][3];
      if (rl) {
        v0 = fmaxf(v0 + b0, 0.f); v1 = fmaxf(v1 + b1, 0.f);
        v2 = fmaxf(v2 + b2, 0.f); v3 = fmaxf(v3 + b3, 0.f);
      }
      wd.b[0] = (__bf16)v0; wd.b[1] = (__bf16)v1;
      wd.b[2] = (__bf16)v2; wd.b[3] = (__bf16)v3;
      *(u32x2*)(Tlds + p * 768 + ((m0 * 2) ^ ((p & 7) << 4))) = wd.u;
    }
  }
  BAR();

  // ---------------- phase 2: out = W2 @ T (barrier-free K loop) -------------
  f32x4 acc2[4][4] = {};
  bf16x8 afA[4], afB[4];
  #pragma unroll
  for (int i = 0; i < 4; ++i)
    afA[i] = *(const bf16x8*)(W2b + ((0 * 32 + wv * 4 + i) << 10) + lane * 16);

  #pragma unroll 1
  for (int g2 = 0; g2 < 6; ++g2) {
    int gA = 2 * g2, gB = 2 * g2 + 1;
    #pragma unroll
    for (int i = 0; i < 4; ++i)
      afB[i] = *(const bf16x8*)(W2b + ((gB * 32 + wv * 4 + i) << 10) + lane * 16);
    {
      bf16x8 bfr[4];
      #pragma unroll
      for (int j = 0; j < 4; ++j) {
        int rb = j * 16 + l15;
        bfr[j] = *(const bf16x8*)(Tlds + rb * 768 +
                                  ((gA * 64 + lg * 16) ^ ((rb & 7) << 4)));
      }
      __builtin_amdgcn_s_setprio(1);
      #pragma unroll
      for (int i = 0; i < 4; ++i)
        #pragma unroll
        for (int j = 0; j < 4; ++j)
          acc2[i][j] = __builtin_amdgcn_mfma_f32_16x16x32_bf16(
              afA[i], bfr[j], acc2[i][j], 0, 0, 0);
      __builtin_amdgcn_s_setprio(0);
    }
    if (g2 < 5) {
      #pragma unroll
      for (int i = 0; i < 4; ++i)
        afA[i] = *(const bf16x8*)(W2b + (((gA + 2) * 32 + wv * 4 + i) << 10) + lane * 16);
    }
    {
      bf16x8 bfr[4];
      #pragma unroll
      for (int j = 0; j < 4; ++j) {
        int rb = j * 16 + l15;
        bfr[j] = *(const bf16x8*)(Tlds + rb * 768 +
                                  ((gB * 64 + lg * 16) ^ ((rb & 7) << 4)));
      }
      __builtin_amdgcn_s_setprio(1);
      #pragma unroll
      for (int i = 0; i < 4; ++i)
        #pragma unroll
        for (int j = 0; j < 4; ++j)
          acc2[i][j] = __builtin_amdgcn_mfma_f32_16x16x32_bf16(
              afB[i], bfr[j], acc2[i][j], 0, 0, 0);
      __builtin_amdgcn_s_setprio(0);
    }
  }

  // epilogue 2: pixel-shuffle scatter. row r = beta*256 + irow*2 + gamma.
  #pragma unroll
  for (int i = 0; i < 4; ++i) {
    int r = (wv * 4 + i) * 16 + lg * 4;   // even
    int beta = r >> 8;
    int irow = (r >> 1) & 127;
    #pragma unroll
    for (int j = 0; j < 4; ++j) {
      int pp = pixbase + j * 16 + l15;
      int h = pp >> 6, w = pp & 63;
      size_t o0 = ((((size_t)img * 128 + irow) * 128) + (2 * h + beta)) * 128
                  + 2 * w;
      f32x2 lo; lo.x = acc2[i][j][0]; lo.y = acc2[i][j][1];
      f32x2 hi; hi.x = acc2[i][j][2]; hi.y = acc2[i][j][3];
      *(f32x2*)(out + o0)         = lo;   // channel irow
      *(f32x2*)(out + o0 + 16384) = hi;   // channel irow+1
    }
  }
}

// ---------------- launcher ---------------------------------------------------

extern "C" void kernel_launch(void* const* d_in, const int* in_sizes, int n_in,
                              void* d_out, int out_size, void* d_ws, size_t ws_size,
                              hipStream_t stream) {
  const float* x     = (const float*)d_in[0];
  const float* w_du  = (const float*)d_in[1];
  const float* b_du  = (const float*)d_in[2];
  const float* w_lr  = (const float*)d_in[3];
  const float* b_lr  = (const float*)d_in[4];
  const float* w_1x1 = (const float*)d_in[5];
  const float* w_ch  = (const float*)d_in[6];
  const float* w_w   = (const float*)d_in[7];
  const float* w_H   = (const float*)d_in[8];
  float* out = (float*)d_out;

  char* ws = (char*)d_ws;
  __bf16* Wf  = (__bf16*)(ws + 0);        // 16*24*1024 = 393216
  __bf16* W2f = (__bf16*)(ws + 393216);   // 12*32*1024 = 393216
  if (ws_size < (size_t)786432) return;

  prep_k <<<1024, 256, 0, stream>>>(w_ch, w_1x1, w_lr, w_du, w_H, w_w, Wf, W2f);
  fused_k<<<512, 512, 0, stream>>>(x, Wf, W2f, b_lr, b_du, out);
}